// Round 1
// baseline (987.767 us; speedup 1.0000x reference)
//
#include <hip/hip_runtime.h>
#include <hip/hip_bf16.h>

#define EPSF 1e-10f
#define CDIM 1000

struct Scalars {
  double ce_tot;            // sum over all elements of y * log(clamp(p))  (negative)
  float umin, umax;
  unsigned label;           // flat argmax of y (first-max semantics)
  unsigned pad;
  float hist[4][22];        // rows: AC, AU, IC, IU ; bins: k0 = 0..21
};

__device__ __forceinline__ void argmax_combine(float& v, unsigned& i, float ov, unsigned oi) {
  if (ov > v || (ov == v && oi < i)) { v = ov; i = oi; }
}

// One wave (64 lanes) per row. Reads probs+y once (float4), produces per-row
// conf/pred/unc and per-block partials {ce(double), y-argmax key(u64), umin, umax}.
__global__ __launch_bounds__(256)
void k_rowstats(const float* __restrict__ probs, const float* __restrict__ y,
                int n, float* __restrict__ conf, float* __restrict__ uncA,
                unsigned* __restrict__ pred,
                double* __restrict__ blk_ce, unsigned long long* __restrict__ blk_key,
                float* __restrict__ blk_umin, float* __restrict__ blk_umax)
{
  const int lane = threadIdx.x & 63;
  const int wid  = threadIdx.x >> 6;
  const int row  = blockIdx.x * 4 + wid;

  __shared__ double s_ce[4];
  __shared__ unsigned long long s_key[4];
  __shared__ float s_umin[4], s_umax[4];
  __shared__ int s_valid[4];

  if (row < n) {
    const float4* p4 = reinterpret_cast<const float4*>(probs + (size_t)row * CDIM);
    const float4* y4 = reinterpret_cast<const float4*>(y + (size_t)row * CDIM);
    float acc_pl = 0.f, acc_yl = 0.f;      // sum p*logp, sum y*logp
    float bv = -1.f;      unsigned bi = 0; // row max / argmax (first)
    float ybv = -1.f;     unsigned ybi = 0; // y row max / argmax (first)
    for (int c = lane; c < CDIM / 4; c += 64) {
      float4 p = p4[c];
      float4 q = y4[c];
      const float pe[4] = {p.x, p.y, p.z, p.w};
      const float qe[4] = {q.x, q.y, q.z, q.w};
#pragma unroll
      for (int e = 0; e < 4; ++e) {
        float pv = pe[e], yv = qe[e];
        float lp = __logf(fmaxf(pv, EPSF));    // log(clamp(p, EPS)) — shared by unc & ce
        acc_pl = fmaf(pv, lp, acc_pl);
        acc_yl = fmaf(yv, lp, acc_yl);
        unsigned j = 4u * (unsigned)c + (unsigned)e;
        if (pv > bv)  { bv = pv;   bi = j; }   // strict > keeps first occurrence
        if (yv > ybv) { ybv = yv;  ybi = j; }
      }
    }
    // wave butterfly all-reduce (64 lanes)
    for (int m = 32; m > 0; m >>= 1) {
      acc_pl += __shfl_xor(acc_pl, m, 64);
      acc_yl += __shfl_xor(acc_yl, m, 64);
      float ov = __shfl_xor(bv, m, 64);  unsigned oi = __shfl_xor(bi, m, 64);
      argmax_combine(bv, bi, ov, oi);
      float oyv = __shfl_xor(ybv, m, 64); unsigned oyi = __shfl_xor(ybi, m, 64);
      argmax_combine(ybv, ybi, oyv, oyi);
    }
    if (lane == 0) {
      float u = -acc_pl;                   // entropy >= 0
      conf[row] = bv;
      pred[row] = bi;
      uncA[row] = u;
      s_ce[wid]  = (double)acc_yl;
      // key: larger y value -> smaller high word; tie -> smaller flat index wins on min
      s_key[wid] = ((unsigned long long)(~__float_as_uint(ybv)) << 32)
                 | (unsigned long long)((unsigned)row * (unsigned)CDIM + ybi);
      s_umin[wid] = u; s_umax[wid] = u;
      s_valid[wid] = 1;
    }
  } else if (lane == 0) {
    s_valid[wid] = 0;
  }
  __syncthreads();
  if (threadIdx.x == 0) {
    double ce = 0.0;
    unsigned long long key = ~0ull;
    float mn = 3.4e38f, mx = -3.4e38f;
#pragma unroll
    for (int w = 0; w < 4; ++w) {
      if (s_valid[w]) {
        ce += s_ce[w];
        if (s_key[w] < key) key = s_key[w];
        mn = fminf(mn, s_umin[w]);
        mx = fmaxf(mx, s_umax[w]);
      }
    }
    blk_ce[blockIdx.x]  = ce;
    blk_key[blockIdx.x] = key;
    blk_umin[blockIdx.x] = mn;
    blk_umax[blockIdx.x] = mx;
  }
}

// Single block: reduce the per-block partials, publish scalars, zero histogram.
__global__ __launch_bounds__(1024)
void k_reduce(const double* __restrict__ blk_ce, const unsigned long long* __restrict__ blk_key,
              const float* __restrict__ blk_umin, const float* __restrict__ blk_umax,
              int nb, Scalars* sc)
{
  __shared__ double sd[1024];
  __shared__ unsigned long long sk[1024];
  __shared__ float smn[1024], smx[1024];
  int t = threadIdx.x;
  double ce = 0.0; unsigned long long key = ~0ull;
  float mn = 3.4e38f, mx = -3.4e38f;
  for (int i = t; i < nb; i += 1024) {
    ce += blk_ce[i];
    unsigned long long k = blk_key[i];
    if (k < key) key = k;
    mn = fminf(mn, blk_umin[i]);
    mx = fmaxf(mx, blk_umax[i]);
  }
  sd[t] = ce; sk[t] = key; smn[t] = mn; smx[t] = mx;
  __syncthreads();
  for (int s = 512; s > 0; s >>= 1) {
    if (t < s) {
      sd[t] += sd[t + s];
      if (sk[t + s] < sk[t]) sk[t] = sk[t + s];
      smn[t] = fminf(smn[t], smn[t + s]);
      smx[t] = fmaxf(smx[t], smx[t + s]);
    }
    __syncthreads();
  }
  if (t == 0) {
    sc->ce_tot = sd[0];
    sc->umin = smn[0];
    sc->umax = smx[0];
    sc->label = (unsigned)(sk[0] & 0xFFFFFFFFull);
  }
  if (t < 88) ((float*)sc->hist)[t] = 0.f;   // zero histogram for k_counters
}

// Histogram over k0 = first threshold index with unc <= th_k (monotone):
// n_ac/n_ic are prefix sums, n_au/n_iu are suffix sums — done in k_final.
__global__ __launch_bounds__(256)
void k_counters(const float* __restrict__ conf, const float* __restrict__ uncA,
                const unsigned* __restrict__ pred, Scalars* __restrict__ sc, int n)
{
  __shared__ float lh[88];
  for (int i = threadIdx.x; i < 88; i += 256) lh[i] = 0.f;
  __syncthreads();
  const float umin = sc->umin, umax = sc->umax;
  const unsigned label = sc->label;
  const float range = umax - umin;
  for (int i = blockIdx.x * 256 + threadIdx.x; i < n; i += gridDim.x * 256) {
    float c = conf[i], u = uncA[i];
    unsigned p = pred[i];
    float t = tanhf(u);
    int k0 = 21;
#pragma unroll
    for (int k = 0; k < 21; ++k) {
      float thv = umin + ((float)k / 20.0f) * range;   // same formula as reference
      if (u <= thv) { k0 = k; break; }
    }
    bool acc = (p == label);
    float w1 = acc ? c * (1.f - t) : (1.f - c) * (1.f - t);  // AC / IC
    float w2 = acc ? c * t        : (1.f - c) * t;           // AU / IU
    int b = acc ? 0 : 2;
    atomicAdd(&lh[b * 22 + k0], w1);
    atomicAdd(&lh[(b + 1) * 22 + k0], w2);
  }
  __syncthreads();
  float* gh = (float*)sc->hist;
  for (int i = threadIdx.x; i < 88; i += 256) {
    if (lh[i] != 0.f) atomicAdd(&gh[i], lh[i]);
  }
}

__global__ void k_final(const Scalars* __restrict__ sc, float* __restrict__ out, int n)
{
  if (threadIdx.x != 0 || blockIdx.x != 0) return;
  const float* hAC = sc->hist[0];
  const float* hAU = sc->hist[1];
  const float* hIC = sc->hist[2];
  const float* hIU = sc->hist[3];
  float totAU = 0.f, totIU = 0.f;
  for (int j = 0; j < 22; ++j) { totAU += hAU[j]; totIU += hIU[j]; }
  float sAC = 0.f, sIC = 0.f, cAU = 0.f, cIU = 0.f;
  float auc = 0.f, prev_avu = 0.f, prev_th = 0.f;
  for (int k = 0; k < 21; ++k) {
    sAC += hAC[k]; sIC += hIC[k]; cAU += hAU[k]; cIU += hIU[k];
    float nac = sAC, nic = sIC;
    float nau = totAU - cAU, niu = totIU - cIU;
    float avu = (nac + niu) / (nac + nau + nic + niu + EPSF);
    float th = (float)k / 20.0f;
    if (k > 0) auc += (avu + prev_avu) * 0.5f * (th - prev_th);  // trapz
    prev_avu = avu; prev_th = th;
  }
  float ce = (float)(-sc->ce_tot / (double)n);
  float avu_loss = -1.0f * logf(auc + EPSF) + ce;   // BETA = 1.0
  out[0] = avu_loss;
  out[1] = ce;
}

extern "C" void kernel_launch(void* const* d_in, const int* in_sizes, int n_in,
                              void* d_out, int out_size, void* d_ws, size_t ws_size,
                              hipStream_t stream) {
  const float* probs = (const float*)d_in[0];
  const float* y     = (const float*)d_in[1];
  const int total = in_sizes[0];
  const int N = total / CDIM;
  const int NB = (N + 3) / 4;

  // ws layout (8B-aligned throughout)
  char* base = (char*)d_ws;
  Scalars* sc = (Scalars*)base;
  double* blk_ce = (double*)(base + 1024);
  unsigned long long* blk_key = (unsigned long long*)(blk_ce + NB);
  float* blk_umin = (float*)(blk_key + NB);
  float* blk_umax = blk_umin + NB;
  float* conf = blk_umax + NB;
  float* uncA = conf + N;
  unsigned* pred = (unsigned*)(uncA + N);

  k_rowstats<<<NB, 256, 0, stream>>>(probs, y, N, conf, uncA, pred,
                                     blk_ce, blk_key, blk_umin, blk_umax);
  k_reduce<<<1, 1024, 0, stream>>>(blk_ce, blk_key, blk_umin, blk_umax, NB, sc);
  k_counters<<<512, 256, 0, stream>>>(conf, uncA, pred, sc, N);
  k_final<<<1, 1, 0, stream>>>(sc, (float*)d_out, N);
}